// Round 5
// baseline (498.809 us; speedup 1.0000x reference)
//
#include <hip/hip_runtime.h>
#include <math.h>

#define DIM   2048
#define NEXP  64
#define NGRP  8
#define GSIZE 8
#define TOPK  8
#define TOPKG 4

#define TM    64             // tokens per block = wavefront size
#define NW    16             // waves per block (K-split 16)
#define KSEG  (DIM / NW)     // 128 k per wave
#define TPB1  1024

// margin thresholds (fp32 score scale). Worst-case score error ~1e-6
// (128-term seq fp32 + ordered 16-way merge); TAU = 40x safety.
// Measured flag rate (r3/r4): ~2.4%.
#define TAU_E 4e-5f
#define TAU_G 8e-5f
#define NEG_INF (-3.4e38f)
#define WLOFF 16
#define WT_OFF (1 << 18)     // Wt at d_ws + 256 KB (wl below it)

// ---------------- kernel 0: W transpose + worklist zero ----------------
__global__ __launch_bounds__(256) void prep_kernel(
    const float* __restrict__ W, float* __restrict__ Wt, int* __restrict__ wl)
{
    const int g = blockIdx.x * 256 + threadIdx.x;   // 0 .. 131071
    const int k = g >> 6, e = g & 63;
    Wt[g] = W[(size_t)e * DIM + k];                 // Wt[k][e] = W[e][k]
    if (g < WLOFF) wl[g] = 0;
}

// ------- kernel 1: lane-per-token GEMV (no LDS in K-loop) + routing -------
__global__ __launch_bounds__(TPB1, 4) void gate_f32_kernel(
    const float* __restrict__ x,
    const float* __restrict__ Wt,     // [DIM][NEXP] transposed weights
    const float* __restrict__ b,
    const float* __restrict__ bias,
    float* __restrict__ out_w,
    float* __restrict__ out_i,
    int* __restrict__ wl)
{
    __shared__ float sMg[NW][TM][8];   // 32 KB merge buffer (8-expert chunks)
    __shared__ float sS[TM][NEXP + 1]; // 16.6 KB score table

    const int tid  = threadIdx.x;
    const int w    = tid >> 6;         // wave id = K segment
    const int lane = tid & 63;         // lane = token within block
    const int tok0 = blockIdx.x * TM;

    // ---- K-loop: acc[e] += x[tok][k] * Wt[k][e], k in [w*KSEG, w*KSEG+KSEG)
    float acc[NEXP];
#pragma unroll
    for (int e = 0; e < NEXP; ++e) acc[e] = 0.f;

    const float* xrow = x + (size_t)(tok0 + lane) * DIM + w * KSEG;
    const float* btseg = Wt + (size_t)(w * KSEG) * NEXP;

    float4 xq = ((const float4*)xrow)[0];
#pragma unroll 1
    for (int s = 0; s < KSEG / 4; ++s) {           // 32 steps of 4 k
        const float4 xc = xq;
        if (s + 1 < KSEG / 4) xq = ((const float4*)xrow)[s + 1];
        const float* bt = btseg + (size_t)(s * 4) * NEXP;
        const float xk[4] = {xc.x, xc.y, xc.z, xc.w};
#pragma unroll
        for (int kk = 0; kk < 4; ++kk) {
            const float xv = xk[kk];
            const float4* br = (const float4*)(bt + kk * NEXP);  // wave-uniform
#pragma unroll
            for (int c = 0; c < 16; ++c) {
                const float4 bv = br[c];
                acc[c * 4 + 0] = fmaf(xv, bv.x, acc[c * 4 + 0]);
                acc[c * 4 + 1] = fmaf(xv, bv.y, acc[c * 4 + 1]);
                acc[c * 4 + 2] = fmaf(xv, bv.z, acc[c * 4 + 2]);
                acc[c * 4 + 3] = fmaf(xv, bv.w, acc[c * 4 + 3]);
            }
        }
    }

    // ---- merge 16 wave-partials, fused sigmoid+bias -> score table ----
    for (int c = 0; c < 8; ++c) {                  // 8 experts per chunk
        float4 v0 = {acc[c*8+0], acc[c*8+1], acc[c*8+2], acc[c*8+3]};
        float4 v1 = {acc[c*8+4], acc[c*8+5], acc[c*8+6], acc[c*8+7]};
        *(float4*)&sMg[w][lane][0] = v0;
        *(float4*)&sMg[w][lane][4] = v1;
        __syncthreads();
        if (tid < TM * 8) {
            const int l = tid >> 3, j = tid & 7;
            float sum = 0.f;
#pragma unroll
            for (int ww = 0; ww < NW; ++ww)        // ordered, deterministic
                sum += sMg[ww][l][j];
            const int e = c * 8 + j;
            const float logit = sum + b[e];
            const float wv = 1.0f / (1.0f + expf(-logit));
            sS[l][e] = wv + bias[e];
        }
        __syncthreads();
    }

    // ---- routing + margin flagging: thread t per token ----
    if (tid < TM) {
        const int t = tid;

        float gs[NGRP];
#pragma unroll
        for (int g = 0; g < NGRP; ++g) {
            float m1 = NEG_INF, m2 = NEG_INF;
#pragma unroll
            for (int j = 0; j < GSIZE; ++j) {
                const float v = sS[t][g * GSIZE + j];
                if (v > m1) { m2 = m1; m1 = v; }
                else if (v > m2) { m2 = v; }
            }
            gs[g] = m1 + m2;
        }

        unsigned gmask = 0u;
        float g4val = NEG_INF;
        for (int rr = 0; rr < TOPKG; ++rr) {
            float best = NEG_INF; int bi = 0;
#pragma unroll
            for (int g = 0; g < NGRP; ++g) {
                const float v = ((gmask >> g) & 1u) ? NEG_INF : gs[g];
                if (v > best) { best = v; bi = g; }
            }
            gmask |= 1u << bi;
            g4val = best;
        }
        float m5 = NEG_INF;
#pragma unroll
        for (int g = 0; g < NGRP; ++g)
            if (!((gmask >> g) & 1u) && gs[g] > m5) m5 = gs[g];
        const float margin_g = g4val - m5;

        unsigned long long chosen = 0ull;
        const size_t obase = (size_t)(tok0 + t) * TOPK;
        float vals[TOPK + 1];
        for (int rr = 0; rr < TOPK + 1; ++rr) {
            float best = NEG_INF; int bi = 0;
            for (int e = 0; e < NEXP; ++e) {
                float v = ((gmask >> (e >> 3)) & 1u) ? sS[t][e] : 0.0f;
                if ((chosen >> e) & 1ull) v = NEG_INF;
                if (v > best) { best = v; bi = e; }
            }
            vals[rr] = best;
            if (rr < TOPK) {
                chosen |= 1ull << (unsigned)bi;
                // weight = sigmoid = score - bias (bias==0 here; <=1ulp general)
                out_w[obase + rr] = ((gmask >> (bi >> 3)) & 1u)
                                  ? (sS[t][bi] - bias[bi]) : 0.0f;
                out_i[obase + rr] = (float)bi;
            }
        }
        float margin_e = 1e30f;
#pragma unroll
        for (int rr = 0; rr < TOPK; ++rr) {
            const float d = vals[rr] - vals[rr + 1];
            if (d < margin_e) margin_e = d;
        }

        if (margin_g < TAU_G || margin_e < TAU_E) {
            const int slot = atomicAdd(wl, 1);
            wl[WLOFF + slot] = tok0 + t;
        }
    }
}

// ---------------- kernel 2: fp64 exact fixup, 1 token per iteration ---------
__global__ __launch_bounds__(256) void gate_fix_kernel(
    const float* __restrict__ x,
    const float* __restrict__ W,
    const float* __restrict__ b,
    const float* __restrict__ bias,
    float* __restrict__ out_w,
    float* __restrict__ out_i,
    const int* __restrict__ wl)
{
    const int count = wl[0];

    __shared__ __align__(16) float sX[DIM];
    __shared__ double sPart[NEXP][4];
    __shared__ float  sS2[NEXP], sW2[NEXP];

    const int tid = threadIdx.x;
    const int e   = tid >> 2;
    const int s   = tid & 3;

    for (int widx = blockIdx.x; widx < count; widx += (int)gridDim.x) {
        const int tok = wl[WLOFF + widx];

        const float4* xr = (const float4*)(x + (size_t)tok * DIM);
        ((float4*)sX)[tid]       = xr[tid];
        ((float4*)sX)[tid + 256] = xr[tid + 256];
        __syncthreads();

        const float4* Wr = (const float4*)(W + (size_t)e * DIM);
        double a0 = 0., a1 = 0., a2 = 0., a3 = 0.;
#pragma unroll 8
        for (int m = 0; m < DIM / 16; ++m) {
            const int c = m * 4 + s;
            const float4 wv = Wr[c];
            const float4 xv = ((const float4*)sX)[c];
            a0 = fma((double)xv.x, (double)wv.x, a0);
            a1 = fma((double)xv.y, (double)wv.y, a1);
            a2 = fma((double)xv.z, (double)wv.z, a2);
            a3 = fma((double)xv.w, (double)wv.w, a3);
        }
        sPart[e][s] = (a0 + a1) + (a2 + a3);
        __syncthreads();

        if (tid < NEXP) {
            const double logit = ((sPart[tid][0] + sPart[tid][1])
                                + (sPart[tid][2] + sPart[tid][3])) + (double)b[tid];
            const float wv = (float)(1.0 / (1.0 + exp(-logit)));
            sW2[tid] = wv;
            sS2[tid] = wv + bias[tid];
        }
        __syncthreads();

        if (tid == 0) {
            float gs[NGRP];
#pragma unroll
            for (int g = 0; g < NGRP; ++g) {
                float m1 = NEG_INF, m2 = NEG_INF;
#pragma unroll
                for (int j = 0; j < GSIZE; ++j) {
                    const float v = sS2[g * GSIZE + j];
                    if (v > m1) { m2 = m1; m1 = v; }
                    else if (v > m2) { m2 = v; }
                }
                gs[g] = m1 + m2;
            }
            unsigned gmask = 0u;
            for (int rr = 0; rr < TOPKG; ++rr) {
                float best = NEG_INF; int bi = 0;
#pragma unroll
                for (int g = 0; g < NGRP; ++g) {
                    const float v = ((gmask >> g) & 1u) ? NEG_INF : gs[g];
                    if (v > best) { best = v; bi = g; }
                }
                gmask |= 1u << bi;
            }
            unsigned long long chosen = 0ull;
            const size_t obase = (size_t)tok * TOPK;
            for (int rr = 0; rr < TOPK; ++rr) {
                float best = NEG_INF; int bi = 0;
                for (int e2 = 0; e2 < NEXP; ++e2) {
                    float v = ((gmask >> (e2 >> 3)) & 1u) ? sS2[e2] : 0.0f;
                    if ((chosen >> e2) & 1ull) v = NEG_INF;
                    if (v > best) { best = v; bi = e2; }
                }
                chosen |= 1ull << (unsigned)bi;
                out_w[obase + rr] = ((gmask >> (bi >> 3)) & 1u) ? sW2[bi] : 0.0f;
                out_i[obase + rr] = (float)bi;
            }
        }
        __syncthreads();
    }
}

extern "C" void kernel_launch(void* const* d_in, const int* in_sizes, int n_in,
                              void* d_out, int out_size, void* d_ws, size_t ws_size,
                              hipStream_t stream) {
    const float* x    = (const float*)d_in[0];
    const float* W    = (const float*)d_in[1];
    const float* b    = (const float*)d_in[2];
    const float* bias = (const float*)d_in[3];

    const int n = in_sizes[0] / DIM;   // 16384 tokens
    float* out_w = (float*)d_out;
    float* out_i = out_w + (size_t)n * TOPK;
    int*   wl    = (int*)d_ws;                          // worklist
    float* Wt    = (float*)((char*)d_ws + WT_OFF);      // 512 KB transposed W

    prep_kernel<<<dim3((NEXP * DIM) / 256), dim3(256), 0, stream>>>(W, Wt, wl);
    gate_f32_kernel<<<dim3(n / TM), dim3(TPB1), 0, stream>>>(
        x, Wt, b, bias, out_w, out_i, wl);
    gate_fix_kernel<<<dim3(1024), dim3(256), 0, stream>>>(
        x, W, b, bias, out_w, out_i, wl);
}

// Round 6
// 304.900 us; speedup vs baseline: 1.6360x; 1.6360x over previous
//
#include <hip/hip_runtime.h>
#include <math.h>

#define DIM   2048
#define NEXP  64
#define NGRP  8
#define GSIZE 8
#define TOPK  8
#define TOPKG 4

#define TM    64             // tokens per block = wavefront size
#define NW    16             // waves per block (K-split 16)
#define KSEG  (DIM / NW)     // 128 k per wave
#define TPB1  1024

// margin thresholds (fp32 score scale). Worst-case score error ~1e-6
// (128-term seq fp32 + ordered 16-way merge); TAU = 40x safety.
// Measured flag rate (r3/r4): ~2.4%.
#define TAU_E 4e-5f
#define TAU_G 8e-5f
#define NEG_INF (-3.4e38f)
#define WLOFF 16
#define WT_OFF (1 << 18)     // Wt at d_ws + 256 KB

// ---------------- kernel 0: W transpose + worklist zero ----------------
__global__ __launch_bounds__(256) void prep_kernel(
    const float* __restrict__ W, float* __restrict__ Wt, int* __restrict__ wl)
{
    const int g = blockIdx.x * 256 + threadIdx.x;   // 0 .. 131071
    const int k = g >> 6, e = g & 63;
    Wt[g] = W[(size_t)e * DIM + k];                 // Wt[k][e] = W[e][k]
    if (g < WLOFF) wl[g] = 0;
}

// ------- kernel 1: lane-per-token GEMV, W via scalar loads + routing -------
__global__ __launch_bounds__(TPB1, 4) void gate_f32_kernel(
    const float* __restrict__ x,
    const float* __restrict__ Wt,     // [DIM][NEXP] transposed weights
    const float* __restrict__ b,
    const float* __restrict__ bias,
    float* __restrict__ out_w,
    float* __restrict__ out_i,
    int* __restrict__ wl)
{
    __shared__ float sMg[NW][TM][8];   // 32 KB merge buffer (8-expert chunks)
    __shared__ float sS[TM][NEXP + 1]; // score table

    const int tid  = threadIdx.x;
    // readfirstlane makes the wave id PROVABLY uniform -> Wt loads scalarize
    // to s_load (round-5 failure: tid-derived address kept them as per-lane
    // vector loads of the same address, 2080 serialized L2 hits per wave).
    const int w    = __builtin_amdgcn_readfirstlane(tid >> 6);
    const int lane = tid & 63;         // lane = token within block
    const int tok0 = blockIdx.x * TM;

    float acc[NEXP];
#pragma unroll
    for (int e = 0; e < NEXP; ++e) acc[e] = 0.f;

    const float* xrow  = x + (size_t)(tok0 + lane) * DIM + w * KSEG;
    const float* btseg = Wt + (size_t)(w * KSEG) * NEXP;   // uniform base

    float4 xq = ((const float4*)xrow)[0];
#pragma unroll 1
    for (int s = 0; s < KSEG / 4; ++s) {           // 32 steps of 4 k
        const float4 xc = xq;
        if (s + 1 < KSEG / 4) xq = ((const float4*)xrow)[s + 1];
        const float xk[4] = {xc.x, xc.y, xc.z, xc.w};
#pragma unroll
        for (int kk = 0; kk < 4; ++kk) {
            const float xv = xk[kk];
            // wave-uniform row of 64 floats (256 B) -> s_load_dwordx16 x4
            const float4* br = (const float4*)(btseg + (size_t)(s * 4 + kk) * NEXP);
#pragma unroll
            for (int c = 0; c < 16; ++c) {
                const float4 bv = br[c];
                acc[c * 4 + 0] = fmaf(xv, bv.x, acc[c * 4 + 0]);
                acc[c * 4 + 1] = fmaf(xv, bv.y, acc[c * 4 + 1]);
                acc[c * 4 + 2] = fmaf(xv, bv.z, acc[c * 4 + 2]);
                acc[c * 4 + 3] = fmaf(xv, bv.w, acc[c * 4 + 3]);
            }
        }
    }

    // ---- merge 16 wave-partials, fused sigmoid+bias -> score table ----
    for (int c = 0; c < 8; ++c) {                  // 8 experts per chunk
        float4 v0 = {acc[c*8+0], acc[c*8+1], acc[c*8+2], acc[c*8+3]};
        float4 v1 = {acc[c*8+4], acc[c*8+5], acc[c*8+6], acc[c*8+7]};
        *(float4*)&sMg[w][lane][0] = v0;
        *(float4*)&sMg[w][lane][4] = v1;
        __syncthreads();
        if (tid < TM * 8) {
            const int l = tid >> 3, j = tid & 7;
            float sum = 0.f;
#pragma unroll
            for (int ww = 0; ww < NW; ++ww)        // ordered, deterministic
                sum += sMg[ww][l][j];
            const int e = c * 8 + j;
            const float logit = sum + b[e];
            const float wv = 1.0f / (1.0f + expf(-logit));
            sS[l][e] = wv + bias[e];
        }
        __syncthreads();
    }

    // ---- routing + margin flagging: thread t per token ----
    if (tid < TM) {
        const int t = tid;

        float gs[NGRP];
#pragma unroll
        for (int g = 0; g < NGRP; ++g) {
            float m1 = NEG_INF, m2 = NEG_INF;
#pragma unroll
            for (int j = 0; j < GSIZE; ++j) {
                const float v = sS[t][g * GSIZE + j];
                if (v > m1) { m2 = m1; m1 = v; }
                else if (v > m2) { m2 = v; }
            }
            gs[g] = m1 + m2;
        }

        unsigned gmask = 0u;
        float g4val = NEG_INF;
        for (int rr = 0; rr < TOPKG; ++rr) {
            float best = NEG_INF; int bi = 0;
#pragma unroll
            for (int g = 0; g < NGRP; ++g) {
                const float v = ((gmask >> g) & 1u) ? NEG_INF : gs[g];
                if (v > best) { best = v; bi = g; }
            }
            gmask |= 1u << bi;
            g4val = best;
        }
        float m5 = NEG_INF;
#pragma unroll
        for (int g = 0; g < NGRP; ++g)
            if (!((gmask >> g) & 1u) && gs[g] > m5) m5 = gs[g];
        const float margin_g = g4val - m5;

        unsigned long long chosen = 0ull;
        const size_t obase = (size_t)(tok0 + t) * TOPK;
        float vals[TOPK + 1];
        for (int rr = 0; rr < TOPK + 1; ++rr) {
            float best = NEG_INF; int bi = 0;
            for (int e = 0; e < NEXP; ++e) {
                float v = ((gmask >> (e >> 3)) & 1u) ? sS[t][e] : 0.0f;
                if ((chosen >> e) & 1ull) v = NEG_INF;
                if (v > best) { best = v; bi = e; }
            }
            vals[rr] = best;
            if (rr < TOPK) {
                chosen |= 1ull << (unsigned)bi;
                // weight = sigmoid = score - bias (bias==0 here; <=1ulp general)
                out_w[obase + rr] = ((gmask >> (bi >> 3)) & 1u)
                                  ? (sS[t][bi] - bias[bi]) : 0.0f;
                out_i[obase + rr] = (float)bi;
            }
        }
        float margin_e = 1e30f;
#pragma unroll
        for (int rr = 0; rr < TOPK; ++rr) {
            const float d = vals[rr] - vals[rr + 1];
            if (d < margin_e) margin_e = d;
        }

        if (margin_g < TAU_G || margin_e < TAU_E) {
            const int slot = atomicAdd(wl, 1);
            wl[WLOFF + slot] = tok0 + t;
        }
    }
}

// ---------------- kernel 2: fp64 exact fixup, 1 token per iteration ---------
__global__ __launch_bounds__(256) void gate_fix_kernel(
    const float* __restrict__ x,
    const float* __restrict__ W,
    const float* __restrict__ b,
    const float* __restrict__ bias,
    float* __restrict__ out_w,
    float* __restrict__ out_i,
    const int* __restrict__ wl)
{
    const int count = wl[0];

    __shared__ __align__(16) float sX[DIM];
    __shared__ double sPart[NEXP][4];
    __shared__ float  sS2[NEXP], sW2[NEXP];

    const int tid = threadIdx.x;
    const int e   = tid >> 2;
    const int s   = tid & 3;

    for (int widx = blockIdx.x; widx < count; widx += (int)gridDim.x) {
        const int tok = wl[WLOFF + widx];

        const float4* xr = (const float4*)(x + (size_t)tok * DIM);
        ((float4*)sX)[tid]       = xr[tid];
        ((float4*)sX)[tid + 256] = xr[tid + 256];
        __syncthreads();

        const float4* Wr = (const float4*)(W + (size_t)e * DIM);
        double a0 = 0., a1 = 0., a2 = 0., a3 = 0.;
#pragma unroll 8
        for (int m = 0; m < DIM / 16; ++m) {
            const int c = m * 4 + s;
            const float4 wv = Wr[c];
            const float4 xv = ((const float4*)sX)[c];
            a0 = fma((double)xv.x, (double)wv.x, a0);
            a1 = fma((double)xv.y, (double)wv.y, a1);
            a2 = fma((double)xv.z, (double)wv.z, a2);
            a3 = fma((double)xv.w, (double)wv.w, a3);
        }
        sPart[e][s] = (a0 + a1) + (a2 + a3);
        __syncthreads();

        if (tid < NEXP) {
            const double logit = ((sPart[tid][0] + sPart[tid][1])
                                + (sPart[tid][2] + sPart[tid][3])) + (double)b[tid];
            const float wv = (float)(1.0 / (1.0 + exp(-logit)));
            sW2[tid] = wv;
            sS2[tid] = wv + bias[tid];
        }
        __syncthreads();

        if (tid == 0) {
            float gs[NGRP];
#pragma unroll
            for (int g = 0; g < NGRP; ++g) {
                float m1 = NEG_INF, m2 = NEG_INF;
#pragma unroll
                for (int j = 0; j < GSIZE; ++j) {
                    const float v = sS2[g * GSIZE + j];
                    if (v > m1) { m2 = m1; m1 = v; }
                    else if (v > m2) { m2 = v; }
                }
                gs[g] = m1 + m2;
            }
            unsigned gmask = 0u;
            for (int rr = 0; rr < TOPKG; ++rr) {
                float best = NEG_INF; int bi = 0;
#pragma unroll
                for (int g = 0; g < NGRP; ++g) {
                    const float v = ((gmask >> g) & 1u) ? NEG_INF : gs[g];
                    if (v > best) { best = v; bi = g; }
                }
                gmask |= 1u << bi;
            }
            unsigned long long chosen = 0ull;
            const size_t obase = (size_t)tok * TOPK;
            for (int rr = 0; rr < TOPK; ++rr) {
                float best = NEG_INF; int bi = 0;
                for (int e2 = 0; e2 < NEXP; ++e2) {
                    float v = ((gmask >> (e2 >> 3)) & 1u) ? sS2[e2] : 0.0f;
                    if ((chosen >> e2) & 1ull) v = NEG_INF;
                    if (v > best) { best = v; bi = e2; }
                }
                chosen |= 1ull << (unsigned)bi;
                out_w[obase + rr] = ((gmask >> (bi >> 3)) & 1u) ? sW2[bi] : 0.0f;
                out_i[obase + rr] = (float)bi;
            }
        }
        __syncthreads();
    }
}

extern "C" void kernel_launch(void* const* d_in, const int* in_sizes, int n_in,
                              void* d_out, int out_size, void* d_ws, size_t ws_size,
                              hipStream_t stream) {
    const float* x    = (const float*)d_in[0];
    const float* W    = (const float*)d_in[1];
    const float* b    = (const float*)d_in[2];
    const float* bias = (const float*)d_in[3];

    const int n = in_sizes[0] / DIM;   // 16384 tokens
    float* out_w = (float*)d_out;
    float* out_i = out_w + (size_t)n * TOPK;
    int*   wl    = (int*)d_ws;                          // worklist
    float* Wt    = (float*)((char*)d_ws + WT_OFF);      // 512 KB transposed W

    prep_kernel<<<dim3((NEXP * DIM) / 256), dim3(256), 0, stream>>>(W, Wt, wl);
    gate_f32_kernel<<<dim3(n / TM), dim3(TPB1), 0, stream>>>(
        x, Wt, b, bias, out_w, out_i, wl);
    gate_fix_kernel<<<dim3(1024), dim3(256), 0, stream>>>(
        x, W, b, bias, out_w, out_i, wl);
}

// Round 7
// 278.734 us; speedup vs baseline: 1.7896x; 1.0939x over previous
//
#include <hip/hip_runtime.h>
#include <math.h>

#define DIM   2048
#define NEXP  64
#define NGRP  8
#define GSIZE 8
#define TOPK  8
#define TOPKG 4

#define TPB1  1024
#define NKS   8              // K-slices per block (one per wave-pair group)
#define KSL   (DIM / NKS)    // 256 k per slice
#define SMSTR 1092           // 16*68+4 floats: bank-rotating k-slice stride

// margin thresholds (fp32 score scale). bf16-split GEMM logit error ~5e-6
// (dropped lo*lo 2^-18/term + fp32 MFMA accum) -> ~1.3e-6 score; ref ~3e-7.
// TAU ~ 30x the 5-sigma combined error. Expected flag rate ~4%.
#define TAU_E 6e-5f
#define TAU_G 1.2e-4f
#define NEG_INF (-3.4e38f)
#define WLOFF 16
#define WT_OFF (1 << 18)     // Wf at d_ws + 256 KB (512 KB of packed B-frags)

typedef __attribute__((ext_vector_type(8)))  short bf16x8;   // 8 bf16 (4 VGPR)
typedef __attribute__((ext_vector_type(16))) float f32x16;   // 32x32 C/D

union FragU { bf16x8 v; unsigned short u[8]; };

static __device__ __forceinline__ unsigned short bf16_rne(float f) {
    unsigned u = __builtin_bit_cast(unsigned, f);
    u += 0x7FFFu + ((u >> 16) & 1u);
    return (unsigned short)(u >> 16);
}
static __device__ __forceinline__ float bf16_to_f(unsigned short h) {
    unsigned u = ((unsigned)h) << 16;
    return __builtin_bit_cast(float, u);
}

// ---- kernel 0: pack W into B-fragment layout (hi/lo bf16) + zero worklist --
// B-frag for mfma_f32_32x32x16_bf16: B[k][n], n = lane&31, k = (lane>>5)*8+j.
// Wf element index: (((h*2 + n2)*128 + kc)*64 + lane)*8 + j   (ushorts)
__global__ __launch_bounds__(256) void prep_kernel(
    const float* __restrict__ W, unsigned short* __restrict__ Wf,
    int* __restrict__ wl)
{
    const int g = blockIdx.x * 256 + threadIdx.x;   // 0..131071
    const int e = g >> 11, k = g & 2047;
    const float w = W[g];                            // W[e][k], coalesced
    const unsigned short hi = bf16_rne(w);
    const unsigned short lo = bf16_rne(w - bf16_to_f(hi));
    const int n2 = e >> 5, lcol = e & 31;
    const int kc = k >> 4, khalf = (k >> 3) & 1, j = k & 7;
    const int lane = (khalf << 5) | lcol;
    Wf[((((0 * 2 + n2) * 128 + kc) << 6) + lane) * 8 + j] = hi;
    Wf[((((1 * 2 + n2) * 128 + kc) << 6) + lane) * 8 + j] = lo;
    if (g < WLOFF) wl[g] = 0;
}

// ---- kernel 1: bf16-split MFMA GEMM + merge + routing + margin flag -------
__global__ __launch_bounds__(TPB1, 4) void gate_kernel(
    const float* __restrict__ x,
    const unsigned short* __restrict__ Wf,
    const float* __restrict__ b,
    const float* __restrict__ bias,
    float* __restrict__ out_w,
    float* __restrict__ out_i,
    int* __restrict__ wl)
{
    __shared__ float sM[NKS * SMSTR];    // 34.9 KB merge buffer
    __shared__ float sS[64][65];         // 16.6 KB score table

    const int tid  = threadIdx.x;
    const int w    = tid >> 6;
    const int lane = tid & 63;
    const int m    = w >> 3;             // M-tile: tokens [32m, 32m+32)
    const int ks   = w & 7;              // K-slice: k in [256ks, 256ks+256)
    const int tok0 = blockIdx.x * 64;
    const int l31  = lane & 31, lh = lane >> 5;

    // A operand: A[row = lane&31][k-run = (lane>>5)*8 + j]
    const float* xr = x + (size_t)(tok0 + 32 * m + l31) * DIM + ks * KSL + lh * 8;
    const bf16x8* Wfv = (const bf16x8*)Wf;   // 16 B per element

    f32x16 acc0, acc1;
#pragma unroll
    for (int z = 0; z < 16; ++z) { acc0[z] = 0.f; acc1[z] = 0.f; }

    float4 p0 = *(const float4*)(xr + 0);
    float4 p1 = *(const float4*)(xr + 4);
    float4 p2 = *(const float4*)(xr + 16);
    float4 p3 = *(const float4*)(xr + 20);

#pragma unroll 1
    for (int i = 0; i < 8; ++i) {        // 2 chunks of K=16 per iteration
        const float4 c00 = p0, c01 = p1, c10 = p2, c11 = p3;
        if (i + 1 < 8) {
            p0 = *(const float4*)(xr + 32 * (i + 1) + 0);
            p1 = *(const float4*)(xr + 32 * (i + 1) + 4);
            p2 = *(const float4*)(xr + 32 * (i + 1) + 16);
            p3 = *(const float4*)(xr + 32 * (i + 1) + 20);
        }
        const int kc0 = ks * 16 + 2 * i;

#pragma unroll
        for (int c = 0; c < 2; ++c) {
            const int kc = kc0 + c;
            const float4 qa = c ? c10 : c00;
            const float4 qb = c ? c11 : c01;
            const float xv[8] = {qa.x, qa.y, qa.z, qa.w, qb.x, qb.y, qb.z, qb.w};
            FragU ah, al;
#pragma unroll
            for (int j = 0; j < 8; ++j) {
                const unsigned short h = bf16_rne(xv[j]);
                ah.u[j] = (short)h;
                al.u[j] = (short)bf16_rne(xv[j] - bf16_to_f(h));
            }
            // B frags (pre-packed, L1/L2-hot): idx = ((h*2+nt)*128 + kc)*64 + lane
            const bf16x8 bh0 = Wfv[((0 * 2 + 0) * 128 + kc) * 64 + lane];
            const bf16x8 bh1 = Wfv[((0 * 2 + 1) * 128 + kc) * 64 + lane];
            const bf16x8 bl0 = Wfv[((1 * 2 + 0) * 128 + kc) * 64 + lane];
            const bf16x8 bl1 = Wfv[((1 * 2 + 1) * 128 + kc) * 64 + lane];

            acc0 = __builtin_amdgcn_mfma_f32_32x32x16_bf16(ah.v, bh0, acc0, 0, 0, 0);
            acc0 = __builtin_amdgcn_mfma_f32_32x32x16_bf16(ah.v, bl0, acc0, 0, 0, 0);
            acc0 = __builtin_amdgcn_mfma_f32_32x32x16_bf16(al.v, bh0, acc0, 0, 0, 0);
            acc1 = __builtin_amdgcn_mfma_f32_32x32x16_bf16(ah.v, bh1, acc1, 0, 0, 0);
            acc1 = __builtin_amdgcn_mfma_f32_32x32x16_bf16(ah.v, bl1, acc1, 0, 0, 0);
            acc1 = __builtin_amdgcn_mfma_f32_32x32x16_bf16(al.v, bh1, acc1, 0, 0, 0);
        }
    }

    // ---- merge 8 K-slice partials (4 rounds x 16 tokens), fused sigmoid ----
    // C/D layout (m74/m101-verified): col = lane&31, row = (reg&3)+8*(reg>>2)+4*(lane>>5)
#pragma unroll
    for (int r = 0; r < 4; ++r) {
#pragma unroll
        for (int jj = 0; jj < 4; ++jj) {
            const int t16 = 8 * m + jj + 4 * lh;       // row-in-round
            sM[ks * SMSTR + t16 * 68 + l31]      = acc0[4 * r + jj];
            sM[ks * SMSTR + t16 * 68 + l31 + 32] = acc1[4 * r + jj];
        }
        __syncthreads();
        {
            const int t16 = tid >> 6;                  // 0..15
            const int e   = tid & 63;
            float sum = 0.f;
#pragma unroll
            for (int s = 0; s < NKS; ++s)
                sum += sM[s * SMSTR + t16 * 68 + e];   // ordered, deterministic
            const float logit = sum + b[e];
            const float wv = 1.0f / (1.0f + expf(-logit));
            const int t_blk = 32 * (t16 >> 3) + 8 * r + (t16 & 7);
            sS[t_blk][e] = wv + bias[e];
        }
        __syncthreads();
    }

    // ---- routing + margin flagging: thread t per token (r6-verified) ----
    if (tid < 64) {
        const int t = tid;

        float gs[NGRP];
#pragma unroll
        for (int g = 0; g < NGRP; ++g) {
            float m1 = NEG_INF, m2 = NEG_INF;
#pragma unroll
            for (int j = 0; j < GSIZE; ++j) {
                const float v = sS[t][g * GSIZE + j];
                if (v > m1) { m2 = m1; m1 = v; }
                else if (v > m2) { m2 = v; }
            }
            gs[g] = m1 + m2;
        }

        unsigned gmask = 0u;
        float g4val = NEG_INF;
        for (int rr = 0; rr < TOPKG; ++rr) {
            float best = NEG_INF; int bi = 0;
#pragma unroll
            for (int g = 0; g < NGRP; ++g) {
                const float v = ((gmask >> g) & 1u) ? NEG_INF : gs[g];
                if (v > best) { best = v; bi = g; }
            }
            gmask |= 1u << bi;
            g4val = best;
        }
        float m5 = NEG_INF;
#pragma unroll
        for (int g = 0; g < NGRP; ++g)
            if (!((gmask >> g) & 1u) && gs[g] > m5) m5 = gs[g];
        const float margin_g = g4val - m5;

        unsigned long long chosen = 0ull;
        const size_t obase = (size_t)(tok0 + t) * TOPK;
        float vals[TOPK + 1];
        for (int rr = 0; rr < TOPK + 1; ++rr) {
            float best = NEG_INF; int bi = 0;
            for (int e = 0; e < NEXP; ++e) {
                float v = ((gmask >> (e >> 3)) & 1u) ? sS[t][e] : 0.0f;
                if ((chosen >> e) & 1ull) v = NEG_INF;
                if (v > best) { best = v; bi = e; }
            }
            vals[rr] = best;
            if (rr < TOPK) {
                chosen |= 1ull << (unsigned)bi;
                out_w[obase + rr] = ((gmask >> (bi >> 3)) & 1u)
                                  ? (sS[t][bi] - bias[bi]) : 0.0f;
                out_i[obase + rr] = (float)bi;
            }
        }
        float margin_e = 1e30f;
#pragma unroll
        for (int rr = 0; rr < TOPK; ++rr) {
            const float d = vals[rr] - vals[rr + 1];
            if (d < margin_e) margin_e = d;
        }

        if (margin_g < TAU_G || margin_e < TAU_E) {
            const int slot = atomicAdd(wl, 1);
            wl[WLOFF + slot] = tok0 + t;
        }
    }
}

// ---------------- kernel 2: fp64 exact fixup, 1 token per iteration ---------
__global__ __launch_bounds__(256) void gate_fix_kernel(
    const float* __restrict__ x,
    const float* __restrict__ W,
    const float* __restrict__ b,
    const float* __restrict__ bias,
    float* __restrict__ out_w,
    float* __restrict__ out_i,
    const int* __restrict__ wl)
{
    const int count = wl[0];

    __shared__ __align__(16) float sX[DIM];
    __shared__ double sPart[NEXP][4];
    __shared__ float  sS2[NEXP], sW2[NEXP];

    const int tid = threadIdx.x;
    const int e   = tid >> 2;
    const int s   = tid & 3;

    for (int widx = blockIdx.x; widx < count; widx += (int)gridDim.x) {
        const int tok = wl[WLOFF + widx];

        const float4* xr = (const float4*)(x + (size_t)tok * DIM);
        ((float4*)sX)[tid]       = xr[tid];
        ((float4*)sX)[tid + 256] = xr[tid + 256];
        __syncthreads();

        const float4* Wr = (const float4*)(W + (size_t)e * DIM);
        double a0 = 0., a1 = 0., a2 = 0., a3 = 0.;
#pragma unroll 8
        for (int mm = 0; mm < DIM / 16; ++mm) {
            const int c = mm * 4 + s;
            const float4 wv = Wr[c];
            const float4 xv = ((const float4*)sX)[c];
            a0 = fma((double)xv.x, (double)wv.x, a0);
            a1 = fma((double)xv.y, (double)wv.y, a1);
            a2 = fma((double)xv.z, (double)wv.z, a2);
            a3 = fma((double)xv.w, (double)wv.w, a3);
        }
        sPart[e][s] = (a0 + a1) + (a2 + a3);
        __syncthreads();

        if (tid < NEXP) {
            const double logit = ((sPart[tid][0] + sPart[tid][1])
                                + (sPart[tid][2] + sPart[tid][3])) + (double)b[tid];
            const float wv = (float)(1.0 / (1.0 + exp(-logit)));
            sW2[tid] = wv;
            sS2[tid] = wv + bias[tid];
        }
        __syncthreads();

        if (tid == 0) {
            float gs[NGRP];
#pragma unroll
            for (int g = 0; g < NGRP; ++g) {
                float m1 = NEG_INF, m2 = NEG_INF;
#pragma unroll
                for (int j = 0; j < GSIZE; ++j) {
                    const float v = sS2[g * GSIZE + j];
                    if (v > m1) { m2 = m1; m1 = v; }
                    else if (v > m2) { m2 = v; }
                }
                gs[g] = m1 + m2;
            }
            unsigned gmask = 0u;
            for (int rr = 0; rr < TOPKG; ++rr) {
                float best = NEG_INF; int bi = 0;
#pragma unroll
                for (int g = 0; g < NGRP; ++g) {
                    const float v = ((gmask >> g) & 1u) ? NEG_INF : gs[g];
                    if (v > best) { best = v; bi = g; }
                }
                gmask |= 1u << bi;
            }
            unsigned long long chosen = 0ull;
            const size_t obase = (size_t)tok * TOPK;
            for (int rr = 0; rr < TOPK; ++rr) {
                float best = NEG_INF; int bi = 0;
                for (int e2 = 0; e2 < NEXP; ++e2) {
                    float v = ((gmask >> (e2 >> 3)) & 1u) ? sS2[e2] : 0.0f;
                    if ((chosen >> e2) & 1ull) v = NEG_INF;
                    if (v > best) { best = v; bi = e2; }
                }
                chosen |= 1ull << (unsigned)bi;
                out_w[obase + rr] = ((gmask >> (bi >> 3)) & 1u) ? sW2[bi] : 0.0f;
                out_i[obase + rr] = (float)bi;
            }
        }
        __syncthreads();
    }
}

extern "C" void kernel_launch(void* const* d_in, const int* in_sizes, int n_in,
                              void* d_out, int out_size, void* d_ws, size_t ws_size,
                              hipStream_t stream) {
    const float* x    = (const float*)d_in[0];
    const float* W    = (const float*)d_in[1];
    const float* b    = (const float*)d_in[2];
    const float* bias = (const float*)d_in[3];

    const int n = in_sizes[0] / DIM;   // 16384 tokens
    float* out_w = (float*)d_out;
    float* out_i = out_w + (size_t)n * TOPK;
    int*   wl    = (int*)d_ws;
    unsigned short* Wf = (unsigned short*)((char*)d_ws + WT_OFF);

    prep_kernel<<<dim3((NEXP * DIM) / 256), dim3(256), 0, stream>>>(W, Wf, wl);
    gate_kernel<<<dim3(n / 64), dim3(TPB1), 0, stream>>>(
        x, Wf, b, bias, out_w, out_i, wl);
    gate_fix_kernel<<<dim3(1024), dim3(256), 0, stream>>>(
        x, W, b, bias, out_w, out_i, wl);
}